// Round 4
// baseline (248.673 us; speedup 1.0000x reference)
//
#include <hip/hip_runtime.h>
#include <hip/hip_bf16.h>

// Sizes fixed by the problem.
#define B_  8
#define T_  2048
#define H_  1024
#define M_  256

typedef __bf16 bf16x8 __attribute__((ext_vector_type(8)));
typedef float  f32x4  __attribute__((ext_vector_type(4)));
typedef unsigned short us4 __attribute__((ext_vector_type(4)));
typedef unsigned short us8 __attribute__((ext_vector_type(8)));

__device__ inline unsigned short f2bf(float f) {
    unsigned int u = __builtin_bit_cast(unsigned int, f);
    return (unsigned short)((u + 0x7FFFu + ((u >> 16) & 1u)) >> 16);
}
__device__ inline float bf2f(unsigned short u) {
    unsigned int x = ((unsigned int)u) << 16;
    return __builtin_bit_cast(float, x);
}

// ---------------------------------------------------------------------------
// K_prep: fused {basis cast, coupling transpose-cast, bias GEMV}.
// grid 1280 x 256:
//   blocks [0,1024)    : basisB[b][h][m] (bf16) = cast(basis)
//   blocks [1024,1152) : cplT[b][m][mp]  (bf16) = coupling[b][mp][m]
//   blocks [1152,1280) : bias[b][h] = srg * (re@W_re + im@W_im)
__global__ void k_prep(const float* __restrict__ basis, const float* __restrict__ cpl,
                       const float* __restrict__ W, const float* __restrict__ re,
                       const float* __restrict__ im, const float* __restrict__ g_srg,
                       unsigned short* __restrict__ basisB, unsigned short* __restrict__ cplT,
                       float* __restrict__ bias)
{
    int blk = blockIdx.x;
    int tid = threadIdx.x;
    if (blk < 1024) {
        size_t i = ((size_t)blk * 256 + tid) * 8;
        float4 a = *(const float4*)&basis[i];
        float4 b = *(const float4*)&basis[i + 4];
        us8 o = { f2bf(a.x), f2bf(a.y), f2bf(a.z), f2bf(a.w),
                  f2bf(b.x), f2bf(b.y), f2bf(b.z), f2bf(b.w) };
        *(us8*)&basisB[i] = o;
    } else if (blk < 1152) {
        int idx = blk - 1024;
        int x = idx & 3, y = (idx >> 2) & 3, b = idx >> 4;
        int r0 = x * 64, c0 = y * 64;
        __shared__ float t[64][65];
        #pragma unroll
        for (int i = 0; i < 4; ++i) {
            int u = tid + i * 256;
            int r = u >> 4, c4 = (u & 15) * 4;
            float4 v = *(const float4*)&cpl[((size_t)(b * M_ + r0 + r)) * M_ + c0 + c4];
            t[r][c4] = v.x; t[r][c4 + 1] = v.y; t[r][c4 + 2] = v.z; t[r][c4 + 3] = v.w;
        }
        __syncthreads();
        #pragma unroll
        for (int i = 0; i < 4; ++i) {
            int u = tid + i * 256;
            int m = u >> 4, r4 = (u & 15) * 4;
            us4 o = { f2bf(t[r4][m]), f2bf(t[r4 + 1][m]), f2bf(t[r4 + 2][m]), f2bf(t[r4 + 3][m]) };
            *(us4*)&cplT[((size_t)(b * M_ + c0 + m)) * M_ + r0 + r4] = o;
        }
    } else {
        int idx = blk - 1152;
        int b = idx & 7, h0 = (idx >> 3) * 64;
        int lane = tid & 63, w = tid >> 6;
        int h = h0 + lane;
        float acc = 0.f;
        #pragma unroll 4
        for (int m = w * 64; m < w * 64 + 64; ++m) {
            float rv = re[b * M_ + m], iv = im[b * M_ + m];
            acc += rv * W[(size_t)m * H_ + h] + iv * W[(size_t)(M_ + m) * H_ + h];
        }
        __shared__ float sh[4][64];
        sh[w][lane] = acc;
        __syncthreads();
        if (w == 0)
            bias[b * H_ + h] = g_srg[0] * (sh[0][lane] + sh[1][lane] + sh[2][lane] + sh[3][lane]);
    }
}

// ---------------------------------------------------------------------------
// K1b: b2T[b][n][h] = sum_mp cplT[b][n][mp] * basisB[b][h][mp]   (bf16 MFMA GEMM)
// BM=64 (n), BN=128 (h), BK=64, 4 waves (each 64x32). grid (M/64, H/128, B)
__global__ __launch_bounds__(256) void k_b2(const unsigned short* __restrict__ cplT,
                                            const unsigned short* __restrict__ basisB,
                                            unsigned short* __restrict__ b2T)
{
    const int b = blockIdx.z;
    const int n0 = blockIdx.x * 64;
    const int h0 = blockIdx.y * 128;
    const int tid = threadIdx.x;
    const int lane = tid & 63, w = tid >> 6;

    __shared__ __align__(16) unsigned short As[64][72];
    __shared__ __align__(16) unsigned short Bs[128][72];

    const unsigned short* Ab = cplT + (size_t)(b * M_ + n0) * M_;
    const unsigned short* Bb = basisB + (size_t)(b * H_ + h0) * M_;

    f32x4 acc[4][2];
    #pragma unroll
    for (int i = 0; i < 4; ++i) { acc[i][0] = (f32x4){0,0,0,0}; acc[i][1] = (f32x4){0,0,0,0}; }

    const int rsel = lane & 15;
    const int kgrp = (lane >> 4) * 8;

    for (int k0 = 0; k0 < M_; k0 += 64) {
        #pragma unroll
        for (int i = 0; i < 2; ++i) {
            int u = tid + i * 256;
            int r = u >> 3, c8 = (u & 7) * 8;
            *(us8*)&As[r][c8] = *(const us8*)&Ab[(size_t)r * M_ + k0 + c8];
        }
        #pragma unroll
        for (int i = 0; i < 4; ++i) {
            int u = tid + i * 256;
            int r = u >> 3, c8 = (u & 7) * 8;
            *(us8*)&Bs[r][c8] = *(const us8*)&Bb[(size_t)r * M_ + k0 + c8];
        }
        __syncthreads();
        #pragma unroll
        for (int kk = 0; kk < 2; ++kk) {
            const int kb = kk * 32 + kgrp;
            bf16x8 af[4], bfr[2];
            #pragma unroll
            for (int mi = 0; mi < 4; ++mi) af[mi] = *(const bf16x8*)&As[mi * 16 + rsel][kb];
            #pragma unroll
            for (int ni = 0; ni < 2; ++ni) bfr[ni] = *(const bf16x8*)&Bs[w * 32 + ni * 16 + rsel][kb];
            #pragma unroll
            for (int mi = 0; mi < 4; ++mi)
                #pragma unroll
                for (int ni = 0; ni < 2; ++ni)
                    acc[mi][ni] = __builtin_amdgcn_mfma_f32_16x16x32_bf16(af[mi], bfr[ni], acc[mi][ni], 0, 0, 0);
        }
        __syncthreads();
    }

    unsigned short* ob = b2T + (size_t)(b * M_ + n0) * H_ + h0;
    const int rbase = (lane >> 4) * 4;
    #pragma unroll
    for (int mi = 0; mi < 4; ++mi)
        #pragma unroll
        for (int ni = 0; ni < 2; ++ni)
            #pragma unroll
            for (int r = 0; r < 4; ++r)
                ob[(size_t)(mi * 16 + rbase + r) * H_ + w * 32 + ni * 16 + rsel] = f2bf(acc[mi][ni][r]);
}

// ---------------------------------------------------------------------------
// K2: alpha16[b][t][m] (bf16) = (hs + bu*inc + td*tdn + bias[h]) @ basis2
// NO LDS, NO BARRIERS: each wave owns a 32t x 128m tile; A fragments built
// global->reg with fused gating; B fragments read from L2 (b2T is XCD-resident
// via batch-per-XCD swizzle b = blockIdx.x & 7).
// grid 256 blocks x 256 thr (4 waves: 2 t-subtiles x 2 m-halves).
__global__ __launch_bounds__(256, 1) void k_alpha(
    const float* __restrict__ hs, const float* __restrict__ inc, const float* __restrict__ tdn,
    const unsigned short* __restrict__ b2T, const float* __restrict__ bias,
    const float* __restrict__ g_bu, const float* __restrict__ g_td,
    unsigned short* __restrict__ alpha16)
{
    const int flat = blockIdx.x;
    const int b = flat & 7;                 // batch-per-XCD
    const int t0 = (flat >> 3) * 64;
    const int tid = threadIdx.x;
    const int lane = tid & 63, wid = tid >> 6;
    const int wt = (wid & 1) * 32;          // t-subtile
    const int mh = (wid >> 1) * 128;        // m-half
    const int rsel = lane & 15;
    const int kgo = (lane >> 4) * 8;
    const float bug = g_bu[0], tdg = g_td[0];

    const size_t rb0 = ((size_t)(b * T_) + t0 + wt + rsel) * H_ + kgo;
    const size_t rb1 = rb0 + (size_t)16 * H_;
    const float* hs0 = hs + rb0;  const float* hs1 = hs + rb1;
    const float* in0 = inc + rb0; const float* in1 = inc + rb1;
    const float* td0 = tdn + rb0; const float* td1 = tdn + rb1;
    const float* bib = bias + b * H_ + kgo;
    const unsigned short* Bb = b2T + ((size_t)(b * M_) + mh + rsel) * H_ + kgo;

    f32x4 acc[2][8];
    #pragma unroll
    for (int i = 0; i < 2; ++i)
        #pragma unroll
        for (int j = 0; j < 8; ++j)
            acc[i][j] = (f32x4){0.f, 0.f, 0.f, 0.f};

    #pragma unroll 2
    for (int kb = 0; kb < H_; kb += 32) {
        f32x4 bi0 = *(const f32x4*)(bib + kb);
        f32x4 bi1 = *(const f32x4*)(bib + kb + 4);
        f32x4 a00 = *(const f32x4*)(hs0 + kb), a01 = *(const f32x4*)(hs0 + kb + 4);
        f32x4 e00 = *(const f32x4*)(in0 + kb), e01 = *(const f32x4*)(in0 + kb + 4);
        f32x4 d00 = *(const f32x4*)(td0 + kb), d01 = *(const f32x4*)(td0 + kb + 4);
        f32x4 a10 = *(const f32x4*)(hs1 + kb), a11 = *(const f32x4*)(hs1 + kb + 4);
        f32x4 e10 = *(const f32x4*)(in1 + kb), e11 = *(const f32x4*)(in1 + kb + 4);
        f32x4 d10 = *(const f32x4*)(td1 + kb), d11 = *(const f32x4*)(td1 + kb + 4);

        f32x4 c00 = a00 + bug * e00 + tdg * d00 + bi0;
        f32x4 c01 = a01 + bug * e01 + tdg * d01 + bi1;
        f32x4 c10 = a10 + bug * e10 + tdg * d10 + bi0;
        f32x4 c11 = a11 + bug * e11 + tdg * d11 + bi1;

        bf16x8 af0, af1;
        #pragma unroll
        for (int j = 0; j < 4; ++j) {
            af0[j]     = (__bf16)c00[j];
            af0[j + 4] = (__bf16)c01[j];
            af1[j]     = (__bf16)c10[j];
            af1[j + 4] = (__bf16)c11[j];
        }

        #pragma unroll
        for (int ni = 0; ni < 8; ++ni) {
            bf16x8 bv = *(const bf16x8*)(Bb + (size_t)ni * (16 * H_) + kb);
            acc[0][ni] = __builtin_amdgcn_mfma_f32_16x16x32_bf16(af0, bv, acc[0][ni], 0, 0, 0);
            acc[1][ni] = __builtin_amdgcn_mfma_f32_16x16x32_bf16(af1, bv, acc[1][ni], 0, 0, 0);
        }
    }

    unsigned short* ab = alpha16 + ((size_t)(b * T_) + t0 + wt) * M_ + mh;
    const int rbase = (lane >> 4) * 4;
    #pragma unroll
    for (int ti = 0; ti < 2; ++ti)
        #pragma unroll
        for (int ni = 0; ni < 8; ++ni)
            #pragma unroll
            for (int r = 0; r < 4; ++r)
                ab[(size_t)(ti * 16 + rbase + r) * M_ + ni * 16 + rsel] = f2bf(acc[ti][ni][r]);
}

// ---------------------------------------------------------------------------
// K3: chunked-parallel scan, chunk=64, halo=96 (gamma^96 ~ 4e-5)
// c[b][t][m] = alpha * s,  s = gamma*s + beta*alpha
// grid (T/64, B), block 256 (= m)
__global__ void k_scan(const unsigned short* __restrict__ alpha16, const float* __restrict__ tape_re,
                       const float* __restrict__ g_gr, const float* __restrict__ g_br,
                       unsigned short* __restrict__ cbuf)
{
    int b = blockIdx.y, chunk = blockIdx.x;
    int m = threadIdx.x;
    float graw = g_gr[0], braw = g_br[0];
    float gamma = 1.f / (1.f + __expf(-graw));
    float beta  = log1pf(__expf(braw));
    int t0 = chunk * 64;
    int th = (t0 >= 96) ? (t0 - 96) : 0;
    float s = tape_re[b * M_ + m];
    if (th > 0) s *= __powf(gamma, (float)th);
    const unsigned short* ab = alpha16 + (size_t)b * T_ * M_ + m;
    unsigned short* cb = cbuf + (size_t)b * T_ * M_ + m;
    for (int t = th; t < t0 + 64; ++t) {
        float a = bf2f(ab[(size_t)t * M_]);
        s = gamma * s + beta * a;
        if (t >= t0) cb[(size_t)t * M_] = f2bf(a * s);
    }
}

// ---------------------------------------------------------------------------
// K4: y[b][t][h] = sum_m c[b][t][m] * basis[b][h][m]
// NO LDS, NO BARRIERS: wave tile 16t x 128h; A (cbuf) and B (basisB) straight
// from L2 (both XCD-resident via batch swizzle). Write-bound on 64MB f32 out.
// grid 2048 blocks x 256 thr (4 waves: 2 t-subtiles x 2 h-halves).
__global__ __launch_bounds__(256, 4) void k_y(const unsigned short* __restrict__ cbuf,
                                              const unsigned short* __restrict__ basisB,
                                              float* __restrict__ out)
{
    const int flat = blockIdx.x;
    const int b = flat & 7;                 // batch-per-XCD
    const int q = flat >> 3;
    const int t0 = (q & 63) * 32;
    const int h0 = (q >> 6) * 256;
    const int tid = threadIdx.x;
    const int lane = tid & 63, wid = tid >> 6;
    const int wt = (wid & 1) * 16;
    const int hh = (wid >> 1) * 128;
    const int rsel = lane & 15;
    const int kgo = (lane >> 4) * 8;

    const unsigned short* At = cbuf + ((size_t)(b * T_) + t0 + wt + rsel) * M_ + kgo;
    const unsigned short* Bh = basisB + ((size_t)(b * H_) + h0 + hh + rsel) * M_ + kgo;

    f32x4 acc[8];
    #pragma unroll
    for (int i = 0; i < 8; ++i) acc[i] = (f32x4){0.f, 0.f, 0.f, 0.f};

    #pragma unroll
    for (int kb = 0; kb < M_; kb += 32) {
        bf16x8 af = *(const bf16x8*)(At + kb);
        #pragma unroll
        for (int ni = 0; ni < 8; ++ni) {
            bf16x8 bv = *(const bf16x8*)(Bh + (size_t)ni * (16 * M_) + kb);
            acc[ni] = __builtin_amdgcn_mfma_f32_16x16x32_bf16(af, bv, acc[ni], 0, 0, 0);
        }
    }

    float* ob = out + ((size_t)(b * T_) + t0 + wt) * H_ + h0 + hh;
    const int rbase = (lane >> 4) * 4;
    #pragma unroll
    for (int ni = 0; ni < 8; ++ni)
        #pragma unroll
        for (int r = 0; r < 4; ++r)
            ob[(size_t)(rbase + r) * H_ + ni * 16 + rsel] = acc[ni][r];
}

// ---------------------------------------------------------------------------
extern "C" void kernel_launch(void* const* d_in, const int* in_sizes, int n_in,
                              void* d_out, int out_size, void* d_ws, size_t ws_size,
                              hipStream_t stream)
{
    const float* hs   = (const float*)d_in[0];
    const float* inc  = (const float*)d_in[1];
    const float* tdn  = (const float*)d_in[2];
    const float* basis= (const float*)d_in[3];
    const float* cpl  = (const float*)d_in[4];
    const float* W    = (const float*)d_in[5];
    const float* t_re = (const float*)d_in[6];
    const float* t_im = (const float*)d_in[7];
    const float* g_bu = (const float*)d_in[8];
    const float* g_td = (const float*)d_in[9];
    const float* g_sr = (const float*)d_in[10];
    const float* g_gr = (const float*)d_in[11];
    const float* g_br = (const float*)d_in[12];
    float* out = (float*)d_out;

    char* ws = (char*)d_ws;
    float*          bias   = (float*)(ws);                                    // 32 KB (pad to 64K)
    unsigned short* basisB = (unsigned short*)(ws + (1u << 16));              // 4 MB
    unsigned short* cplT   = (unsigned short*)(ws + (1u << 16) + (4u << 20)); // 1 MB
    unsigned short* b2T    = (unsigned short*)(ws + (1u << 16) + (5u << 20)); // 4 MB
    unsigned short* alpha16= (unsigned short*)(ws + (1u << 16) + (9u << 20)); // 8 MB
    unsigned short* cbuf   = (unsigned short*)(ws + (1u << 16) + (17u << 20));// 8 MB

    k_prep <<<dim3(1280),                  dim3(256), 0, stream>>>(basis, cpl, W, t_re, t_im, g_sr, basisB, cplT, bias);
    k_b2   <<<dim3(M_ / 64, H_ / 128, B_), dim3(256), 0, stream>>>(cplT, basisB, b2T);
    k_alpha<<<dim3(256),                   dim3(256), 0, stream>>>(hs, inc, tdn, b2T, bias, g_bu, g_td, alpha16);
    k_scan <<<dim3(T_ / 64, B_),           dim3(256), 0, stream>>>(alpha16, t_re, g_gr, g_br, cbuf);
    k_y    <<<dim3(2048),                  dim3(256), 0, stream>>>(cbuf, basisB, out);
}

// Round 5
// 216.700 us; speedup vs baseline: 1.1475x; 1.1475x over previous
//
#include <hip/hip_runtime.h>
#include <hip/hip_bf16.h>

// Sizes fixed by the problem.
#define B_  8
#define T_  2048
#define H_  1024
#define M_  256

typedef __bf16 bf16x8 __attribute__((ext_vector_type(8)));
typedef float  f32x4  __attribute__((ext_vector_type(4)));
typedef unsigned short us4 __attribute__((ext_vector_type(4)));
typedef unsigned short us8 __attribute__((ext_vector_type(8)));

__device__ inline unsigned short f2bf(float f) {
    unsigned int u = __builtin_bit_cast(unsigned int, f);
    return (unsigned short)((u + 0x7FFFu + ((u >> 16) & 1u)) >> 16);
}
__device__ inline float bf2f(unsigned short u) {
    unsigned int x = ((unsigned int)u) << 16;
    return __builtin_bit_cast(float, x);
}

// ---------------------------------------------------------------------------
// K_prep: fused {basis cast, coupling transpose-cast, bias GEMV}.
// grid 1280 x 256:
//   blocks [0,1024)    : basisB[b][h][m] (bf16) = cast(basis)
//   blocks [1024,1152) : cplT[b][m][mp]  (bf16) = coupling[b][mp][m]
//   blocks [1152,1280) : bias[b][h] = srg * (re@W_re + im@W_im)
__global__ void k_prep(const float* __restrict__ basis, const float* __restrict__ cpl,
                       const float* __restrict__ W, const float* __restrict__ re,
                       const float* __restrict__ im, const float* __restrict__ g_srg,
                       unsigned short* __restrict__ basisB, unsigned short* __restrict__ cplT,
                       float* __restrict__ bias)
{
    int blk = blockIdx.x;
    int tid = threadIdx.x;
    if (blk < 1024) {
        size_t i = ((size_t)blk * 256 + tid) * 8;
        float4 a = *(const float4*)&basis[i];
        float4 b = *(const float4*)&basis[i + 4];
        us8 o = { f2bf(a.x), f2bf(a.y), f2bf(a.z), f2bf(a.w),
                  f2bf(b.x), f2bf(b.y), f2bf(b.z), f2bf(b.w) };
        *(us8*)&basisB[i] = o;
    } else if (blk < 1152) {
        int idx = blk - 1024;
        int x = idx & 3, y = (idx >> 2) & 3, b = idx >> 4;
        int r0 = x * 64, c0 = y * 64;
        __shared__ float t[64][65];
        #pragma unroll
        for (int i = 0; i < 4; ++i) {
            int u = tid + i * 256;
            int r = u >> 4, c4 = (u & 15) * 4;
            float4 v = *(const float4*)&cpl[((size_t)(b * M_ + r0 + r)) * M_ + c0 + c4];
            t[r][c4] = v.x; t[r][c4 + 1] = v.y; t[r][c4 + 2] = v.z; t[r][c4 + 3] = v.w;
        }
        __syncthreads();
        #pragma unroll
        for (int i = 0; i < 4; ++i) {
            int u = tid + i * 256;
            int m = u >> 4, r4 = (u & 15) * 4;
            us4 o = { f2bf(t[r4][m]), f2bf(t[r4 + 1][m]), f2bf(t[r4 + 2][m]), f2bf(t[r4 + 3][m]) };
            *(us4*)&cplT[((size_t)(b * M_ + c0 + m)) * M_ + r0 + r4] = o;
        }
    } else {
        int idx = blk - 1152;
        int b = idx & 7, h0 = (idx >> 3) * 64;
        int lane = tid & 63, w = tid >> 6;
        int h = h0 + lane;
        float acc = 0.f;
        #pragma unroll 4
        for (int m = w * 64; m < w * 64 + 64; ++m) {
            float rv = re[b * M_ + m], iv = im[b * M_ + m];
            acc += rv * W[(size_t)m * H_ + h] + iv * W[(size_t)(M_ + m) * H_ + h];
        }
        __shared__ float sh[4][64];
        sh[w][lane] = acc;
        __syncthreads();
        if (w == 0)
            bias[b * H_ + h] = g_srg[0] * (sh[0][lane] + sh[1][lane] + sh[2][lane] + sh[3][lane]);
    }
}

// ---------------------------------------------------------------------------
// K1b: b2T[b][n][h] = sum_mp cplT[b][n][mp] * basisB[b][h][mp]   (bf16 MFMA GEMM)
// BM=64 (n), BN=128 (h), BK=64, 4 waves (each 64x32). grid (M/64, H/128, B)
__global__ __launch_bounds__(256) void k_b2(const unsigned short* __restrict__ cplT,
                                            const unsigned short* __restrict__ basisB,
                                            unsigned short* __restrict__ b2T)
{
    const int b = blockIdx.z;
    const int n0 = blockIdx.x * 64;
    const int h0 = blockIdx.y * 128;
    const int tid = threadIdx.x;
    const int lane = tid & 63, w = tid >> 6;

    __shared__ __align__(16) unsigned short As[64][72];
    __shared__ __align__(16) unsigned short Bs[128][72];

    const unsigned short* Ab = cplT + (size_t)(b * M_ + n0) * M_;
    const unsigned short* Bb = basisB + (size_t)(b * H_ + h0) * M_;

    f32x4 acc[4][2];
    #pragma unroll
    for (int i = 0; i < 4; ++i) { acc[i][0] = (f32x4){0,0,0,0}; acc[i][1] = (f32x4){0,0,0,0}; }

    const int rsel = lane & 15;
    const int kgrp = (lane >> 4) * 8;

    for (int k0 = 0; k0 < M_; k0 += 64) {
        #pragma unroll
        for (int i = 0; i < 2; ++i) {
            int u = tid + i * 256;
            int r = u >> 3, c8 = (u & 7) * 8;
            *(us8*)&As[r][c8] = *(const us8*)&Ab[(size_t)r * M_ + k0 + c8];
        }
        #pragma unroll
        for (int i = 0; i < 4; ++i) {
            int u = tid + i * 256;
            int r = u >> 3, c8 = (u & 7) * 8;
            *(us8*)&Bs[r][c8] = *(const us8*)&Bb[(size_t)r * M_ + k0 + c8];
        }
        __syncthreads();
        #pragma unroll
        for (int kk = 0; kk < 2; ++kk) {
            const int kb = kk * 32 + kgrp;
            bf16x8 af[4], bfr[2];
            #pragma unroll
            for (int mi = 0; mi < 4; ++mi) af[mi] = *(const bf16x8*)&As[mi * 16 + rsel][kb];
            #pragma unroll
            for (int ni = 0; ni < 2; ++ni) bfr[ni] = *(const bf16x8*)&Bs[w * 32 + ni * 16 + rsel][kb];
            #pragma unroll
            for (int mi = 0; mi < 4; ++mi)
                #pragma unroll
                for (int ni = 0; ni < 2; ++ni)
                    acc[mi][ni] = __builtin_amdgcn_mfma_f32_16x16x32_bf16(af[mi], bfr[ni], acc[mi][ni], 0, 0, 0);
        }
        __syncthreads();
    }

    unsigned short* ob = b2T + (size_t)(b * M_ + n0) * H_ + h0;
    const int rbase = (lane >> 4) * 4;
    #pragma unroll
    for (int mi = 0; mi < 4; ++mi)
        #pragma unroll
        for (int ni = 0; ni < 2; ++ni)
            #pragma unroll
            for (int r = 0; r < 4; ++r)
                ob[(size_t)(mi * 16 + rbase + r) * H_ + w * 32 + ni * 16 + rsel] = f2bf(acc[mi][ni][r]);
}

// ---------------------------------------------------------------------------
// K2: partial alpha (bf16), no LDS / no barriers, m-split x2 and K-split x2.
// Wave tile: 16 t-rows x 128 m x 512 K. Block = 4 waves over same 16 t-rows:
//   wid&1 -> m-half, wid>>1 -> K-half. grid = B*T/16 = 1024 blocks x 256 thr.
// 4096 waves = 4 waves/SIMD. Partials: pal[kslice] summed later in k_scan.
__global__ __launch_bounds__(256, 4) void k_alpha(
    const float* __restrict__ hs, const float* __restrict__ inc, const float* __restrict__ tdn,
    const unsigned short* __restrict__ b2T, const float* __restrict__ bias,
    const float* __restrict__ g_bu, const float* __restrict__ g_td,
    unsigned short* __restrict__ pal)   // 2 x [B][T][M]
{
    const int flat = blockIdx.x;
    const int b = flat & 7;                 // batch-per-XCD
    const int t0 = (flat >> 3) * 16;
    const int tid = threadIdx.x;
    const int lane = tid & 63, wid = tid >> 6;
    const int mh = (wid & 1) * 128;         // m-half
    const int kh = (wid >> 1) * 512;        // K-half
    const int rsel = lane & 15;
    const int kgo = (lane >> 4) * 8;
    const float bug = g_bu[0], tdg = g_td[0];

    const size_t rb = ((size_t)(b * T_) + t0 + rsel) * H_ + kh + kgo;
    const float* hs0 = hs + rb;
    const float* in0 = inc + rb;
    const float* td0 = tdn + rb;
    const float* bib = bias + b * H_ + kh + kgo;
    const unsigned short* Bb = b2T + ((size_t)(b * M_) + mh + rsel) * H_ + kh + kgo;

    f32x4 acc[8];
    #pragma unroll
    for (int i = 0; i < 8; ++i) acc[i] = (f32x4){0.f, 0.f, 0.f, 0.f};

    #pragma unroll 2
    for (int kb = 0; kb < 512; kb += 32) {
        f32x4 bi0 = *(const f32x4*)(bib + kb);
        f32x4 bi1 = *(const f32x4*)(bib + kb + 4);
        f32x4 a0 = *(const f32x4*)(hs0 + kb), a1 = *(const f32x4*)(hs0 + kb + 4);
        f32x4 e0 = *(const f32x4*)(in0 + kb), e1 = *(const f32x4*)(in0 + kb + 4);
        f32x4 d0 = *(const f32x4*)(td0 + kb), d1 = *(const f32x4*)(td0 + kb + 4);

        f32x4 c0 = a0 + bug * e0 + tdg * d0 + bi0;
        f32x4 c1 = a1 + bug * e1 + tdg * d1 + bi1;

        bf16x8 af;
        #pragma unroll
        for (int j = 0; j < 4; ++j) {
            af[j]     = (__bf16)c0[j];
            af[j + 4] = (__bf16)c1[j];
        }

        #pragma unroll
        for (int ni = 0; ni < 8; ++ni) {
            bf16x8 bv = *(const bf16x8*)(Bb + (size_t)ni * (16 * H_) + kb);
            acc[ni] = __builtin_amdgcn_mfma_f32_16x16x32_bf16(af, bv, acc[ni], 0, 0, 0);
        }
    }

    unsigned short* ab = pal + (size_t)(wid >> 1) * ((size_t)B_ * T_ * M_)
                       + ((size_t)(b * T_) + t0) * M_ + mh;
    const int rbase = (lane >> 4) * 4;
    #pragma unroll
    for (int ni = 0; ni < 8; ++ni)
        #pragma unroll
        for (int r = 0; r < 4; ++r)
            ab[(size_t)(rbase + r) * M_ + ni * 16 + rsel] = f2bf(acc[ni][r]);
}

// ---------------------------------------------------------------------------
// K3: chunked-parallel scan, chunk=64, halo=96 (gamma^96 ~ 4e-5)
// alpha = p0 + p1 (K-split partials); c = alpha*s, s = gamma*s + beta*alpha
// grid (T/64, B), block 256 (= m)
__global__ void k_scan(const unsigned short* __restrict__ pal, const float* __restrict__ tape_re,
                       const float* __restrict__ g_gr, const float* __restrict__ g_br,
                       unsigned short* __restrict__ cbuf)
{
    int b = blockIdx.y, chunk = blockIdx.x;
    int m = threadIdx.x;
    float graw = g_gr[0], braw = g_br[0];
    float gamma = 1.f / (1.f + __expf(-graw));
    float beta  = log1pf(__expf(braw));
    int t0 = chunk * 64;
    int th = (t0 >= 96) ? (t0 - 96) : 0;
    float s = tape_re[b * M_ + m];
    if (th > 0) s *= __powf(gamma, (float)th);
    const size_t PH = (size_t)B_ * T_ * M_;
    const unsigned short* p0 = pal + (size_t)b * T_ * M_ + m;
    const unsigned short* p1 = p0 + PH;
    unsigned short* cb = cbuf + (size_t)b * T_ * M_ + m;
    #pragma unroll 4
    for (int t = th; t < t0 + 64; ++t) {
        float a = bf2f(p0[(size_t)t * M_]) + bf2f(p1[(size_t)t * M_]);
        s = gamma * s + beta * a;
        if (t >= t0) cb[(size_t)t * M_] = f2bf(a * s);
    }
}

// ---------------------------------------------------------------------------
// K4: y[b][t][h] = sum_m c[b][t][m] * basis[b][h][m]
// MFMA bf16 GEMM: BM=128, BN=128, BK=64, K=256; 4 waves 2x2 (each 64x64).
// grid (T/128, H/128, B), block 256
__global__ __launch_bounds__(256) void k_y(const unsigned short* __restrict__ cbuf,
                                           const unsigned short* __restrict__ basisB,
                                           float* __restrict__ out)
{
    const int b = blockIdx.z;
    const int t0 = blockIdx.x * 128;
    const int h0 = blockIdx.y * 128;
    const int tid = threadIdx.x;
    const int lane = tid & 63, w = tid >> 6;
    const int wm = w >> 1, wn = w & 1;

    __shared__ __align__(16) unsigned short As[128][72];
    __shared__ __align__(16) unsigned short Bs[128][72];

    const unsigned short* cb = cbuf + (size_t)(b * T_ + t0) * M_;
    const unsigned short* bb = basisB + (size_t)(b * H_ + h0) * M_;

    f32x4 acc[4][4];
    #pragma unroll
    for (int i = 0; i < 4; ++i)
        #pragma unroll
        for (int j = 0; j < 4; ++j)
            acc[i][j] = (f32x4){0.f, 0.f, 0.f, 0.f};

    const int rsel = lane & 15;
    const int kgrp = (lane >> 4) * 8;

    for (int k0 = 0; k0 < M_; k0 += 64) {
        #pragma unroll
        for (int i = 0; i < 4; ++i) {
            int u = tid + i * 256;
            int r = u >> 3, c8 = (u & 7) * 8;
            *(us8*)&As[r][c8] = *(const us8*)&cb[(size_t)r * M_ + k0 + c8];
        }
        #pragma unroll
        for (int i = 0; i < 4; ++i) {
            int u = tid + i * 256;
            int r = u >> 3, c8 = (u & 7) * 8;
            *(us8*)&Bs[r][c8] = *(const us8*)&bb[(size_t)r * M_ + k0 + c8];
        }
        __syncthreads();
        #pragma unroll
        for (int kk = 0; kk < 2; ++kk) {
            const int kb = kk * 32 + kgrp;
            bf16x8 af[4], bfr[4];
            #pragma unroll
            for (int mi = 0; mi < 4; ++mi) af[mi] = *(const bf16x8*)&As[wm * 64 + mi * 16 + rsel][kb];
            #pragma unroll
            for (int ni = 0; ni < 4; ++ni) bfr[ni] = *(const bf16x8*)&Bs[wn * 64 + ni * 16 + rsel][kb];
            #pragma unroll
            for (int mi = 0; mi < 4; ++mi)
                #pragma unroll
                for (int ni = 0; ni < 4; ++ni)
                    acc[mi][ni] = __builtin_amdgcn_mfma_f32_16x16x32_bf16(af[mi], bfr[ni], acc[mi][ni], 0, 0, 0);
        }
        __syncthreads();
    }

    float* ob = out + (size_t)(b * T_ + t0) * H_ + h0;
    const int rbase = (lane >> 4) * 4;
    #pragma unroll
    for (int mi = 0; mi < 4; ++mi)
        #pragma unroll
        for (int ni = 0; ni < 4; ++ni)
            #pragma unroll
            for (int r = 0; r < 4; ++r)
                ob[(size_t)(wm * 64 + mi * 16 + rbase + r) * H_ + wn * 64 + ni * 16 + rsel] = acc[mi][ni][r];
}

// ---------------------------------------------------------------------------
extern "C" void kernel_launch(void* const* d_in, const int* in_sizes, int n_in,
                              void* d_out, int out_size, void* d_ws, size_t ws_size,
                              hipStream_t stream)
{
    const float* hs   = (const float*)d_in[0];
    const float* inc  = (const float*)d_in[1];
    const float* tdn  = (const float*)d_in[2];
    const float* basis= (const float*)d_in[3];
    const float* cpl  = (const float*)d_in[4];
    const float* W    = (const float*)d_in[5];
    const float* t_re = (const float*)d_in[6];
    const float* t_im = (const float*)d_in[7];
    const float* g_bu = (const float*)d_in[8];
    const float* g_td = (const float*)d_in[9];
    const float* g_sr = (const float*)d_in[10];
    const float* g_gr = (const float*)d_in[11];
    const float* g_br = (const float*)d_in[12];
    float* out = (float*)d_out;

    char* ws = (char*)d_ws;
    float*          bias   = (float*)(ws);                                    // 64 KB slot
    unsigned short* basisB = (unsigned short*)(ws + (1u << 16));              // 4 MB
    unsigned short* cplT   = (unsigned short*)(ws + (1u << 16) + (4u << 20)); // 1 MB
    unsigned short* b2T    = (unsigned short*)(ws + (1u << 16) + (5u << 20)); // 4 MB
    unsigned short* pal    = (unsigned short*)(ws + (1u << 16) + (9u << 20)); // 2 x 8 MB
    unsigned short* cbuf   = (unsigned short*)(ws + (1u << 16) + (25u << 20));// 8 MB

    k_prep <<<dim3(1280),                   dim3(256), 0, stream>>>(basis, cpl, W, t_re, t_im, g_sr, basisB, cplT, bias);
    k_b2   <<<dim3(M_ / 64, H_ / 128, B_),  dim3(256), 0, stream>>>(cplT, basisB, b2T);
    k_alpha<<<dim3(1024),                   dim3(256), 0, stream>>>(hs, inc, tdn, b2T, bias, g_bu, g_td, pal);
    k_scan <<<dim3(T_ / 64, B_),            dim3(256), 0, stream>>>(pal, t_re, g_gr, g_br, cbuf);
    k_y    <<<dim3(T_ / 128, H_ / 128, B_), dim3(256), 0, stream>>>(cbuf, basisB, out);
}

// Round 6
// 169.545 us; speedup vs baseline: 1.4667x; 1.2781x over previous
//
#include <hip/hip_runtime.h>
#include <hip/hip_bf16.h>

// Sizes fixed by the problem.
#define B_  8
#define T_  2048
#define H_  1024
#define M_  256

typedef __bf16 bf16x8 __attribute__((ext_vector_type(8)));
typedef float  f32x4  __attribute__((ext_vector_type(4)));
typedef unsigned short us4 __attribute__((ext_vector_type(4)));
typedef unsigned short us8 __attribute__((ext_vector_type(8)));

__device__ inline unsigned short f2bf(float f) {
    unsigned int u = __builtin_bit_cast(unsigned int, f);
    return (unsigned short)((u + 0x7FFFu + ((u >> 16) & 1u)) >> 16);
}
__device__ inline float bf2f(unsigned short u) {
    unsigned int x = ((unsigned int)u) << 16;
    return __builtin_bit_cast(float, x);
}

// ---------------------------------------------------------------------------
// K_prep: fused {basis cast, coupling transpose-cast, bias GEMV}.
// grid 1280 x 256:
//   blocks [0,1024)    : basisB[b][h][m] (bf16) = cast(basis)
//   blocks [1024,1152) : cplT[b][m][mp]  (bf16) = coupling[b][mp][m]
//   blocks [1152,1280) : bias[b][h] = srg * (re@W_re + im@W_im)
__global__ void k_prep(const float* __restrict__ basis, const float* __restrict__ cpl,
                       const float* __restrict__ W, const float* __restrict__ re,
                       const float* __restrict__ im, const float* __restrict__ g_srg,
                       unsigned short* __restrict__ basisB, unsigned short* __restrict__ cplT,
                       float* __restrict__ bias)
{
    int blk = blockIdx.x;
    int tid = threadIdx.x;
    if (blk < 1024) {
        size_t i = ((size_t)blk * 256 + tid) * 8;
        float4 a = *(const float4*)&basis[i];
        float4 b = *(const float4*)&basis[i + 4];
        us8 o = { f2bf(a.x), f2bf(a.y), f2bf(a.z), f2bf(a.w),
                  f2bf(b.x), f2bf(b.y), f2bf(b.z), f2bf(b.w) };
        *(us8*)&basisB[i] = o;
    } else if (blk < 1152) {
        int idx = blk - 1024;
        int x = idx & 3, y = (idx >> 2) & 3, b = idx >> 4;
        int r0 = x * 64, c0 = y * 64;
        __shared__ float t[64][65];
        #pragma unroll
        for (int i = 0; i < 4; ++i) {
            int u = tid + i * 256;
            int r = u >> 4, c4 = (u & 15) * 4;
            float4 v = *(const float4*)&cpl[((size_t)(b * M_ + r0 + r)) * M_ + c0 + c4];
            t[r][c4] = v.x; t[r][c4 + 1] = v.y; t[r][c4 + 2] = v.z; t[r][c4 + 3] = v.w;
        }
        __syncthreads();
        #pragma unroll
        for (int i = 0; i < 4; ++i) {
            int u = tid + i * 256;
            int m = u >> 4, r4 = (u & 15) * 4;
            us4 o = { f2bf(t[r4][m]), f2bf(t[r4 + 1][m]), f2bf(t[r4 + 2][m]), f2bf(t[r4 + 3][m]) };
            *(us4*)&cplT[((size_t)(b * M_ + c0 + m)) * M_ + r0 + r4] = o;
        }
    } else {
        int idx = blk - 1152;
        int b = idx & 7, h0 = (idx >> 3) * 64;
        int lane = tid & 63, w = tid >> 6;
        int h = h0 + lane;
        float acc = 0.f;
        #pragma unroll 4
        for (int m = w * 64; m < w * 64 + 64; ++m) {
            float rv = re[b * M_ + m], iv = im[b * M_ + m];
            acc += rv * W[(size_t)m * H_ + h] + iv * W[(size_t)(M_ + m) * H_ + h];
        }
        __shared__ float sh[4][64];
        sh[w][lane] = acc;
        __syncthreads();
        if (w == 0)
            bias[b * H_ + h] = g_srg[0] * (sh[0][lane] + sh[1][lane] + sh[2][lane] + sh[3][lane]);
    }
}

// ---------------------------------------------------------------------------
// K1b: b2T[b][n][h] = sum_mp cplT[b][n][mp] * basisB[b][h][mp]   (bf16 MFMA GEMM)
// BM=64 (n), BN=128 (h), BK=64, 4 waves (each 64x32). grid (M/64, H/128, B)
__global__ __launch_bounds__(256) void k_b2(const unsigned short* __restrict__ cplT,
                                            const unsigned short* __restrict__ basisB,
                                            unsigned short* __restrict__ b2T)
{
    const int b = blockIdx.z;
    const int n0 = blockIdx.x * 64;
    const int h0 = blockIdx.y * 128;
    const int tid = threadIdx.x;
    const int lane = tid & 63, w = tid >> 6;

    __shared__ __align__(16) unsigned short As[64][72];
    __shared__ __align__(16) unsigned short Bs[128][72];

    const unsigned short* Ab = cplT + (size_t)(b * M_ + n0) * M_;
    const unsigned short* Bb = basisB + (size_t)(b * H_ + h0) * M_;

    f32x4 acc[4][2];
    #pragma unroll
    for (int i = 0; i < 4; ++i) { acc[i][0] = (f32x4){0,0,0,0}; acc[i][1] = (f32x4){0,0,0,0}; }

    const int rsel = lane & 15;
    const int kgrp = (lane >> 4) * 8;

    for (int k0 = 0; k0 < M_; k0 += 64) {
        #pragma unroll
        for (int i = 0; i < 2; ++i) {
            int u = tid + i * 256;
            int r = u >> 3, c8 = (u & 7) * 8;
            *(us8*)&As[r][c8] = *(const us8*)&Ab[(size_t)r * M_ + k0 + c8];
        }
        #pragma unroll
        for (int i = 0; i < 4; ++i) {
            int u = tid + i * 256;
            int r = u >> 3, c8 = (u & 7) * 8;
            *(us8*)&Bs[r][c8] = *(const us8*)&Bb[(size_t)r * M_ + k0 + c8];
        }
        __syncthreads();
        #pragma unroll
        for (int kk = 0; kk < 2; ++kk) {
            const int kb = kk * 32 + kgrp;
            bf16x8 af[4], bfr[2];
            #pragma unroll
            for (int mi = 0; mi < 4; ++mi) af[mi] = *(const bf16x8*)&As[mi * 16 + rsel][kb];
            #pragma unroll
            for (int ni = 0; ni < 2; ++ni) bfr[ni] = *(const bf16x8*)&Bs[w * 32 + ni * 16 + rsel][kb];
            #pragma unroll
            for (int mi = 0; mi < 4; ++mi)
                #pragma unroll
                for (int ni = 0; ni < 2; ++ni)
                    acc[mi][ni] = __builtin_amdgcn_mfma_f32_16x16x32_bf16(af[mi], bfr[ni], acc[mi][ni], 0, 0, 0);
        }
        __syncthreads();
    }

    unsigned short* ob = b2T + (size_t)(b * M_ + n0) * H_ + h0;
    const int rbase = (lane >> 4) * 4;
    #pragma unroll
    for (int mi = 0; mi < 4; ++mi)
        #pragma unroll
        for (int ni = 0; ni < 2; ++ni)
            #pragma unroll
            for (int r = 0; r < 4; ++r)
                ob[(size_t)(mi * 16 + rbase + r) * H_ + w * 32 + ni * 16 + rsel] = f2bf(acc[mi][ni][r]);
}

// ---------------------------------------------------------------------------
// K2: alpha16[b][t][m] (bf16) = (hs + bu*inc + td*tdn + bias[h]) @ basis2
// Hybrid: A staged in LDS (coalesced f32 loads + fused gating, BK=128);
// B fragments read DIRECTLY from L2 (b2T is XCD-resident: batch-per-XCD
// swizzle b = blockIdx.x & 7 and b2T[b] = 512 KB < 4 MB L2).
// BM=32, BN=256; 256 thr = 4 waves, wave = 32t x 64m, 8 barrier-steps total.
// grid 512 blocks -> 2 blocks/CU (barrier bubbles overlap across blocks).
__global__ __launch_bounds__(256, 2) void k_alpha(
    const float* __restrict__ hs, const float* __restrict__ inc, const float* __restrict__ tdn,
    const unsigned short* __restrict__ b2T, const float* __restrict__ bias,
    const float* __restrict__ g_bu, const float* __restrict__ g_td,
    unsigned short* __restrict__ alpha16)
{
    const int flat = blockIdx.x;
    const int b = flat & 7;                 // batch-per-XCD
    const int t0 = (flat >> 3) * 32;
    const int tid = threadIdx.x;
    const int lane = tid & 63, wid = tid >> 6;   // wid = m-quarter
    const int rsel = lane & 15;
    const int kgo = (lane >> 4) * 8;
    const float bug = g_bu[0], tdg = g_td[0];

    __shared__ __align__(16) unsigned short As[32][136];   // BK=128, pitch 136

    const float* hsb = hs  + (size_t)(b * T_ + t0) * H_;
    const float* inb = inc + (size_t)(b * T_ + t0) * H_;
    const float* tdb = tdn + (size_t)(b * T_ + t0) * H_;
    const float* bib = bias + (size_t)b * H_;
    const unsigned short* Bb = b2T + ((size_t)(b * M_) + wid * 64 + rsel) * H_ + kgo;

    f32x4 acc[2][4];
    #pragma unroll
    for (int i = 0; i < 2; ++i)
        #pragma unroll
        for (int j = 0; j < 4; ++j)
            acc[i][j] = (f32x4){0.f, 0.f, 0.f, 0.f};

    // staging coords: each thread covers row sr, 16 cols starting at sc
    const int sr = tid >> 3;             // 0..31
    const int sc = (tid & 7) * 16;       // 0,16,...,112

    for (int k0 = 0; k0 < H_; k0 += 128) {
        // stage A: 32 rows x 128 cols, coalesced f32 loads, fused gating
        #pragma unroll
        for (int j = 0; j < 4; ++j) {
            size_t g = (size_t)sr * H_ + k0 + sc + j * 4;
            float4 a  = *(const float4*)(hsb + g);
            float4 e  = *(const float4*)(inb + g);
            float4 d  = *(const float4*)(tdb + g);
            float4 bi = *(const float4*)(bib + k0 + sc + j * 4);
            us4 o = { f2bf(a.x + bug * e.x + tdg * d.x + bi.x),
                      f2bf(a.y + bug * e.y + tdg * d.y + bi.y),
                      f2bf(a.z + bug * e.z + tdg * d.z + bi.z),
                      f2bf(a.w + bug * e.w + tdg * d.w + bi.w) };
            *(us4*)&As[sr][sc + j * 4] = o;
        }
        __syncthreads();
        #pragma unroll
        for (int kk = 0; kk < 4; ++kk) {
            const int kb = kk * 32 + kgo;
            bf16x8 af0 = *(const bf16x8*)&As[rsel][kb];
            bf16x8 af1 = *(const bf16x8*)&As[16 + rsel][kb];
            #pragma unroll
            for (int ni = 0; ni < 4; ++ni) {
                bf16x8 bv = *(const bf16x8*)(Bb + (size_t)ni * (16 * H_) + k0 + kk * 32);
                acc[0][ni] = __builtin_amdgcn_mfma_f32_16x16x32_bf16(af0, bv, acc[0][ni], 0, 0, 0);
                acc[1][ni] = __builtin_amdgcn_mfma_f32_16x16x32_bf16(af1, bv, acc[1][ni], 0, 0, 0);
            }
        }
        __syncthreads();
    }

    unsigned short* ab = alpha16 + (size_t)(b * T_ + t0) * M_ + wid * 64;
    const int rbase = (lane >> 4) * 4;
    #pragma unroll
    for (int mi = 0; mi < 2; ++mi)
        #pragma unroll
        for (int ni = 0; ni < 4; ++ni)
            #pragma unroll
            for (int r = 0; r < 4; ++r)
                ab[(size_t)(mi * 16 + rbase + r) * M_ + ni * 16 + rsel] = f2bf(acc[mi][ni][r]);
}

// ---------------------------------------------------------------------------
// K3: chunked-parallel scan, chunk=64, halo=96 (gamma^96 ~ 4e-5)
// c[b][t][m] = alpha * s,  s = gamma*s + beta*alpha
// grid (T/64, B), block 256 (= m)
__global__ void k_scan(const unsigned short* __restrict__ alpha16, const float* __restrict__ tape_re,
                       const float* __restrict__ g_gr, const float* __restrict__ g_br,
                       unsigned short* __restrict__ cbuf)
{
    int b = blockIdx.y, chunk = blockIdx.x;
    int m = threadIdx.x;
    float graw = g_gr[0], braw = g_br[0];
    float gamma = 1.f / (1.f + __expf(-graw));
    float beta  = log1pf(__expf(braw));
    int t0 = chunk * 64;
    int th = (t0 >= 96) ? (t0 - 96) : 0;
    float s = tape_re[b * M_ + m];
    if (th > 0) s *= __powf(gamma, (float)th);
    const unsigned short* ab = alpha16 + (size_t)b * T_ * M_ + m;
    unsigned short* cb = cbuf + (size_t)b * T_ * M_ + m;
    #pragma unroll 4
    for (int t = th; t < t0 + 64; ++t) {
        float a = bf2f(ab[(size_t)t * M_]);
        s = gamma * s + beta * a;
        if (t >= t0) cb[(size_t)t * M_] = f2bf(a * s);
    }
}

// ---------------------------------------------------------------------------
// K4: y[b][t][h] = sum_m c[b][t][m] * basis[b][h][m]
// MFMA bf16 GEMM: BM=128, BN=128, BK=64, K=256; 4 waves 2x2 (each 64x64).
// Batch-per-XCD swizzle (cbuf 1MB + basisB 512KB per batch -> L2-resident).
// grid 1024 flat, block 256
__global__ __launch_bounds__(256) void k_y(const unsigned short* __restrict__ cbuf,
                                           const unsigned short* __restrict__ basisB,
                                           float* __restrict__ out)
{
    const int flat = blockIdx.x;
    const int b = flat & 7;
    const int q = flat >> 3;
    const int t0 = (q & 15) * 128;
    const int h0 = (q >> 4) * 128;
    const int tid = threadIdx.x;
    const int lane = tid & 63, w = tid >> 6;
    const int wm = w >> 1, wn = w & 1;

    __shared__ __align__(16) unsigned short As[128][72];
    __shared__ __align__(16) unsigned short Bs[128][72];

    const unsigned short* cb = cbuf + (size_t)(b * T_ + t0) * M_;
    const unsigned short* bb = basisB + (size_t)(b * H_ + h0) * M_;

    f32x4 acc[4][4];
    #pragma unroll
    for (int i = 0; i < 4; ++i)
        #pragma unroll
        for (int j = 0; j < 4; ++j)
            acc[i][j] = (f32x4){0.f, 0.f, 0.f, 0.f};

    const int rsel = lane & 15;
    const int kgrp = (lane >> 4) * 8;

    for (int k0 = 0; k0 < M_; k0 += 64) {
        #pragma unroll
        for (int i = 0; i < 4; ++i) {
            int u = tid + i * 256;
            int r = u >> 3, c8 = (u & 7) * 8;
            *(us8*)&As[r][c8] = *(const us8*)&cb[(size_t)r * M_ + k0 + c8];
        }
        #pragma unroll
        for (int i = 0; i < 4; ++i) {
            int u = tid + i * 256;
            int r = u >> 3, c8 = (u & 7) * 8;
            *(us8*)&Bs[r][c8] = *(const us8*)&bb[(size_t)r * M_ + k0 + c8];
        }
        __syncthreads();
        #pragma unroll
        for (int kk = 0; kk < 2; ++kk) {
            const int kb = kk * 32 + kgrp;
            bf16x8 af[4], bfr[4];
            #pragma unroll
            for (int mi = 0; mi < 4; ++mi) af[mi] = *(const bf16x8*)&As[wm * 64 + mi * 16 + rsel][kb];
            #pragma unroll
            for (int ni = 0; ni < 4; ++ni) bfr[ni] = *(const bf16x8*)&Bs[wn * 64 + ni * 16 + rsel][kb];
            #pragma unroll
            for (int mi = 0; mi < 4; ++mi)
                #pragma unroll
                for (int ni = 0; ni < 4; ++ni)
                    acc[mi][ni] = __builtin_amdgcn_mfma_f32_16x16x32_bf16(af[mi], bfr[ni], acc[mi][ni], 0, 0, 0);
        }
        __syncthreads();
    }

    float* ob = out + (size_t)(b * T_ + t0) * H_ + h0;
    const int rbase = (lane >> 4) * 4;
    #pragma unroll
    for (int mi = 0; mi < 4; ++mi)
        #pragma unroll
        for (int ni = 0; ni < 4; ++ni)
            #pragma unroll
            for (int r = 0; r < 4; ++r)
                ob[(size_t)(wm * 64 + mi * 16 + rbase + r) * H_ + wn * 64 + ni * 16 + rsel] = acc[mi][ni][r];
}

// ---------------------------------------------------------------------------
extern "C" void kernel_launch(void* const* d_in, const int* in_sizes, int n_in,
                              void* d_out, int out_size, void* d_ws, size_t ws_size,
                              hipStream_t stream)
{
    const float* hs   = (const float*)d_in[0];
    const float* inc  = (const float*)d_in[1];
    const float* tdn  = (const float*)d_in[2];
    const float* basis= (const float*)d_in[3];
    const float* cpl  = (const float*)d_in[4];
    const float* W    = (const float*)d_in[5];
    const float* t_re = (const float*)d_in[6];
    const float* t_im = (const float*)d_in[7];
    const float* g_bu = (const float*)d_in[8];
    const float* g_td = (const float*)d_in[9];
    const float* g_sr = (const float*)d_in[10];
    const float* g_gr = (const float*)d_in[11];
    const float* g_br = (const float*)d_in[12];
    float* out = (float*)d_out;

    char* ws = (char*)d_ws;
    float*          bias   = (float*)(ws);                                    // 64 KB slot
    unsigned short* basisB = (unsigned short*)(ws + (1u << 16));              // 4 MB
    unsigned short* cplT   = (unsigned short*)(ws + (1u << 16) + (4u << 20)); // 1 MB
    unsigned short* b2T    = (unsigned short*)(ws + (1u << 16) + (5u << 20)); // 4 MB
    unsigned short* alpha16= (unsigned short*)(ws + (1u << 16) + (9u << 20)); // 8 MB
    unsigned short* cbuf   = (unsigned short*)(ws + (1u << 16) + (17u << 20));// 8 MB

    k_prep <<<dim3(1280),                  dim3(256), 0, stream>>>(basis, cpl, W, t_re, t_im, g_sr, basisB, cplT, bias);
    k_b2   <<<dim3(M_ / 64, H_ / 128, B_), dim3(256), 0, stream>>>(cplT, basisB, b2T);
    k_alpha<<<dim3(512),                   dim3(256), 0, stream>>>(hs, inc, tdn, b2T, bias, g_bu, g_td, alpha16);
    k_scan <<<dim3(T_ / 64, B_),           dim3(256), 0, stream>>>(alpha16, t_re, g_gr, g_br, cbuf);
    k_y    <<<dim3(1024),                  dim3(256), 0, stream>>>(cbuf, basisB, out);
}